// Round 2
// 374.387 us; speedup vs baseline: 1.0167x; 1.0167x over previous
//
#include <hip/hip_runtime.h>
#include <hip/hip_bf16.h>
#include <stdint.h>

// GRUModel: y[t,b,:] = GRUCell(x[t,b,:], hid[t,b,:]) per (t,b). M = T*B = 131072, H = I = 128.
//
// Structure (v2.1): weights-as-A-operand, resident in VGPRs.
//   - 512-thread block = 8 waves; wave w owns h-cols [w*16, w*16+16) for ALL 6 gates.
//   - Per wave: 24 bf16 A-fragments (6 gates x 4 k-steps) = 96 VGPRs, loaded once per block.
//   - Block covers all 128 h-cols -> x/hid fetched from HBM exactly once (was 4x in round 0).
//   - No LDS, no barriers. Per 16-row tile: convert(cur) -> prefetch(next) -> 24 MFMA -> epilogue.
//   - D layout (16x16x32 bf16): row(m)=q*4+reg = h-subcol, col(n)=lane&15 = batch row
//     -> one f32x4 store for y and one for hout per lane per tile.
//   - hout write fused with the epilogue's hid read (separate copy pass deleted).
//   - bf16 convert via __float2bfloat16 scalar casts (compiler packs to v_cvt_pk_bf16_f32;
//     hand-written inline asm removed — slower per guide m240 and the only exotic instr).

typedef __attribute__((ext_vector_type(8))) short short8;   // 8 bf16 = 4 VGPRs
typedef __attribute__((ext_vector_type(4))) float f32x4;

#define GRID 512   // 2 blocks/CU serially; 8192 tiles -> 16 tiles/block

__device__ __forceinline__ float fast_sigmoid(float v) {
    return 1.0f / (1.0f + __expf(-v));
}
__device__ __forceinline__ float fast_tanh(float v) {
    return 2.0f / (1.0f + __expf(-2.0f * v)) - 1.0f;  // inf-safe
}

// fp32 -> bf16 (RNE) via HW cvt; compiler fuses pairs into v_cvt_pk_bf16_f32
__device__ __forceinline__ short f2bf(float f) {
    __hip_bfloat16 b = __float2bfloat16(f);
    union { __hip_bfloat16 b; short s; } u; u.b = b;
    return u.s;
}

__device__ __forceinline__ short8 pack8(f32x4 a, f32x4 b) {
    short8 r;
    r[0] = f2bf(a[0]); r[1] = f2bf(a[1]); r[2] = f2bf(a[2]); r[3] = f2bf(a[3]);
    r[4] = f2bf(b[0]); r[5] = f2bf(b[1]); r[6] = f2bf(b[2]); r[7] = f2bf(b[3]);
    return r;
}

__global__ __launch_bounds__(512) void gru_kernel(
    const float* __restrict__ x,
    const float* __restrict__ hid,
    const float* __restrict__ Wih,
    const float* __restrict__ Whh,
    const float* __restrict__ bih,
    const float* __restrict__ bhh,
    float* __restrict__ y,
    float* __restrict__ hout,
    int ntiles, int tpb)
{
    const int tid  = threadIdx.x;
    const int lane = tid & 63;
    const int w    = tid >> 6;       // wave 0..7 -> h-cols w*16..w*16+15
    const int l15  = lane & 15;
    const int q    = lane >> 4;      // quad 0..3

    // ---- weights -> VGPR A-fragments (one-time; L2-resident fp32 source) ----
    // A-frag for 16x16x32: lane l15 = m (h-subcol), holds k = s*32 + q*8 .. +7
    short8 wf[6][4];                 // g = {i_r,i_z,i_n,h_r,h_z,h_n}; 96 VGPRs
    #pragma unroll
    for (int g = 0; g < 6; ++g) {
        const float* Wp  = (g < 3) ? Wih : Whh;
        const float* src = Wp + (size_t)((g % 3) * 128 + w * 16 + l15) * 128 + q * 8;
        #pragma unroll
        for (int s = 0; s < 4; ++s) {
            f32x4 a = *(const f32x4*)(src + s * 32);
            f32x4 b = *(const f32x4*)(src + s * 32 + 4);
            wf[g][s] = pack8(a, b);
        }
    }

    // ---- per-lane biases for this lane's 4 h-cols (h0 .. h0+3) ----
    const int h0 = w * 16 + q * 4;
    f32x4 br4  = *(const f32x4*)(bih + h0)       + *(const f32x4*)(bhh + h0);
    f32x4 bz4  = *(const f32x4*)(bih + 128 + h0) + *(const f32x4*)(bhh + 128 + h0);
    f32x4 bin4 = *(const f32x4*)(bih + 256 + h0);
    f32x4 bhn4 = *(const f32x4*)(bhh + 256 + h0);

    // ---- tile range for this block (16 rows per tile, contiguous) ----
    const int t0 = blockIdx.x * tpb;
    const int t1 = (t0 + tpb < ntiles) ? (t0 + tpb) : ntiles;
    if (t0 >= t1) return;

    // B-frag loads: lane l15 = n (batch row), k = s*32 + q*8 .. +7
    const float* xp  = x   + (size_t)(t0 * 16 + l15) * 128 + q * 8;
    const float* hp  = hid + (size_t)(t0 * 16 + l15) * 128 + q * 8;
    const float* hvp = hid + (size_t)(t0 * 16 + l15) * 128 + h0;   // epilogue blend + hout
    float*       yp  = y    + (size_t)(t0 * 16 + l15) * 128 + h0;
    float*       op  = hout + (size_t)(t0 * 16 + l15) * 128 + h0;

    // ---- preload tile t0 (fp32 raw) ----
    f32x4 xr[4][2], hr[4][2], hv;
    #pragma unroll
    for (int s = 0; s < 4; ++s) {
        xr[s][0] = *(const f32x4*)(xp + s * 32);
        xr[s][1] = *(const f32x4*)(xp + s * 32 + 4);
        hr[s][0] = *(const f32x4*)(hp + s * 32);
        hr[s][1] = *(const f32x4*)(hp + s * 32 + 4);
    }
    hv = *(const f32x4*)hvp;

    for (int t = t0; t < t1; ++t) {
        // -- convert current tile to bf16 fragments (frees xr/hr for prefetch) --
        short8 xa[4], ha[4];
        #pragma unroll
        for (int s = 0; s < 4; ++s) {
            xa[s] = pack8(xr[s][0], xr[s][1]);
            ha[s] = pack8(hr[s][0], hr[s][1]);
        }
        f32x4 hvc = hv;

        // -- issue next tile's loads (overlap with MFMA + epilogue below) --
        if (t + 1 < t1) {
            xp += 2048; hp += 2048; hvp += 2048;     // 16 rows * 128 floats
            #pragma unroll
            for (int s = 0; s < 4; ++s) {
                xr[s][0] = *(const f32x4*)(xp + s * 32);
                xr[s][1] = *(const f32x4*)(xp + s * 32 + 4);
                hr[s][0] = *(const f32x4*)(hp + s * 32);
                hr[s][1] = *(const f32x4*)(hp + s * 32 + 4);
            }
            hv = *(const f32x4*)hvp;
        }

        // -- 24 MFMAs: D[m=h-subcol][n=batch row] --
        f32x4 acc[6];
        #pragma unroll
        for (int g = 0; g < 6; ++g) acc[g] = (f32x4){0.f, 0.f, 0.f, 0.f};
        #pragma unroll
        for (int s = 0; s < 4; ++s) {
            #pragma unroll
            for (int g = 0; g < 6; ++g) {
                acc[g] = __builtin_amdgcn_mfma_f32_16x16x32_bf16(
                    wf[g][s], (g < 3) ? xa[s] : ha[s], acc[g], 0, 0, 0);
            }
        }

        // -- epilogue: lane = batch row l15, h-cols h0..h0+3 (r = reg idx) --
        f32x4 yv;
        #pragma unroll
        for (int r = 0; r < 4; ++r) {
            float rv = fast_sigmoid(acc[0][r] + acc[3][r] + br4[r]);
            float zv = fast_sigmoid(acc[1][r] + acc[4][r] + bz4[r]);
            float nv = fast_tanh(acc[2][r] + bin4[r] + rv * (acc[5][r] + bhn4[r]));
            yv[r] = (1.0f - zv) * nv + zv * hvc[r];
        }
        *(f32x4*)yp = yv;      // 16B store; 4 lanes/row -> 64B contiguous per row
        *(f32x4*)op = hvc;     // hout = exact fp32 hid copy (fused, no extra read)
        yp += 2048; op += 2048;
    }
}

extern "C" void kernel_launch(void* const* d_in, const int* in_sizes, int n_in,
                              void* d_out, int out_size, void* d_ws, size_t ws_size,
                              hipStream_t stream) {
    const float* x   = (const float*)d_in[0];
    const float* hid = (const float*)d_in[1];
    const float* Wih = (const float*)d_in[2];
    const float* Whh = (const float*)d_in[3];
    const float* bih = (const float*)d_in[4];
    const float* bhh = (const float*)d_in[5];

    const int M = in_sizes[0] / 128;               // T*B = 131072
    float* y    = (float*)d_out;
    float* hout = y + (size_t)M * 128;

    const int ntiles = M / 16;                     // 8192 row-tiles
    int grid = GRID;
    if (grid > ntiles) grid = ntiles;
    const int tpb = (ntiles + grid - 1) / grid;    // 16 tiles/block at M=131072

    gru_kernel<<<grid, 512, 0, stream>>>(x, hid, Wih, Whh, bih, bhh, y, hout, ntiles, tpb);
}

// Round 4
// 286.977 us; speedup vs baseline: 1.3263x; 1.3046x over previous
//
#include <hip/hip_runtime.h>
#include <hip/hip_bf16.h>
#include <stdint.h>

// GRUModel: y[t,b,:] = GRUCell(x[t,b,:], hid[t,b,:]) per (t,b). M = T*B = 131072, H = I = 128.
//
// v3.1: identical to v3 except __launch_bounds__(512) — round 3's (512,8) forced a 64-VGPR
// cap (min-waves/EU semantics), guaranteeing massive scratch spill -> timeout -> container kill.
//
// Structure: LDS-staged bf16 tiles, conversion-once, fully-coalesced global access.
//   - 512 threads = 8 waves; wave w owns h-cols [w*16,w*16+16); weights resident in VGPRs (96/wave).
//   - Staging: waves 0-3 load x, 4-7 load hid. Linear 1KB-contiguous f32x4 loads (8 full lines
//     per instr), cvt to bf16 ONCE, 8B writes into XOR-swizzled LDS ([row][col^((row&7)<<4)]).
//   - Double-buffered LDS (2 x 8KB bf16) + double-buffered stage regs (prefetch t+1 issued a
//     full tile before use). One __syncthreads per tile (write(b)/read(b) separated by the
//     other buffer's barrier).
//   - Fragment reads: swizzled ds_read_b128 delivers 8 bf16 ready for MFMA (no consume-side cvt).
//   - hout: hid-stager waves store their fp32 stage regs straight to hout (exact, coalesced,
//     zero extra reads). hv (blend) re-reads hid fp32 (L1/L2-hit; exactness needed).
//   - 1024 blocks x 8 tiles; 16KB LDS, ~210 VGPR -> 1 block/CU resident (8 waves/CU), no spill.

typedef __attribute__((ext_vector_type(8))) short short8;    // 8 bf16 = 4 VGPRs
typedef __attribute__((ext_vector_type(4))) short short4v;   // 4 bf16 = 2 VGPRs
typedef __attribute__((ext_vector_type(4))) float f32x4;

#define GRID 1024

__device__ __forceinline__ float fast_sigmoid(float v) {
    return 1.0f / (1.0f + __expf(-v));
}
__device__ __forceinline__ float fast_tanh(float v) {
    return 2.0f / (1.0f + __expf(-2.0f * v)) - 1.0f;  // inf-safe
}

// fp32 -> bf16 (RNE) via HW cvt; compiler packs pairs into v_cvt_pk_bf16_f32
__device__ __forceinline__ short f2bf(float f) {
    union { __hip_bfloat16 b; short s; } u; u.b = __float2bfloat16(f);
    return u.s;
}
__device__ __forceinline__ short8 pack8(f32x4 a, f32x4 b) {
    short8 r;
    r[0] = f2bf(a[0]); r[1] = f2bf(a[1]); r[2] = f2bf(a[2]); r[3] = f2bf(a[3]);
    r[4] = f2bf(b[0]); r[5] = f2bf(b[1]); r[6] = f2bf(b[2]); r[7] = f2bf(b[3]);
    return r;
}
__device__ __forceinline__ short4v cvt4(f32x4 a) {
    short4v r;
    r[0] = f2bf(a[0]); r[1] = f2bf(a[1]); r[2] = f2bf(a[2]); r[3] = f2bf(a[3]);
    return r;
}

// One tile's compute phase: frag reads from LBUF, 24 MFMA, gate math, y store.
// S0/S1 are the fp32 stage regs of the CURRENT tile (hid-stager waves store them to hout).
#define COMPUTE_TILE(LBUF, S0, S1)                                             \
    {                                                                          \
        f32x4 hv = *(const f32x4*)hvp;                   /* issue early */     \
        if (w >= 4) {                                    /* hout from regs */  \
            *(f32x4*)houtp         = (S0);                                     \
            *(f32x4*)(houtp + 256) = (S1);                                     \
        }                                                                      \
        short8 xa[4], ha[4];                                                   \
        _Pragma("unroll")                                                      \
        for (int s = 0; s < 4; ++s) {                                          \
            xa[s] = *(const short8*)((LBUF) + xoff[s]);                        \
            ha[s] = *(const short8*)((LBUF) + xoff[s] + 4096);                 \
        }                                                                      \
        f32x4 acc[6];                                                          \
        _Pragma("unroll")                                                      \
        for (int g = 0; g < 6; ++g) acc[g] = (f32x4){0.f, 0.f, 0.f, 0.f};      \
        _Pragma("unroll")                                                      \
        for (int s = 0; s < 4; ++s) {                                          \
            _Pragma("unroll")                                                  \
            for (int g = 0; g < 6; ++g) {                                      \
                acc[g] = __builtin_amdgcn_mfma_f32_16x16x32_bf16(              \
                    wf[g][s], (g < 3) ? xa[s] : ha[s], acc[g], 0, 0, 0);       \
            }                                                                  \
        }                                                                      \
        f32x4 yv;                                                              \
        _Pragma("unroll")                                                      \
        for (int r = 0; r < 4; ++r) {                                          \
            float rv = fast_sigmoid(acc[0][r] + acc[3][r] + br4[r]);           \
            float zv = fast_sigmoid(acc[1][r] + acc[4][r] + bz4[r]);           \
            float nv = fast_tanh(acc[2][r] + bin4[r] + rv * (acc[5][r] + bhn4[r])); \
            yv[r] = (1.0f - zv) * nv + zv * hv[r];                             \
        }                                                                      \
        *(f32x4*)yp = yv;                                                      \
        hvp += 2048; yp += 2048; houtp += 2048;                                \
    }

__global__ __launch_bounds__(512) void gru_kernel(
    const float* __restrict__ x,
    const float* __restrict__ hid,
    const float* __restrict__ Wih,
    const float* __restrict__ Whh,
    const float* __restrict__ bih,
    const float* __restrict__ bhh,
    float* __restrict__ y,
    float* __restrict__ hout,
    int ntiles, int tpb)
{
    // [buf][ x:0..4095 | hid:4096..8191 ] bf16, rows of 256B, swizzle col^((row&7)<<4)
    __shared__ __align__(16) char lds[2][8192];

    const int tid  = threadIdx.x;
    const int lane = tid & 63;
    const int w    = tid >> 6;       // wave 0..7 -> h-cols w*16..w*16+15
    const int l15  = lane & 15;
    const int q    = lane >> 4;      // quad 0..3

    // ---- weights -> VGPR A-fragments (one-time; layout verified in round 2) ----
    short8 wf[6][4];                 // g = {i_r,i_z,i_n,h_r,h_z,h_n}
    #pragma unroll
    for (int g = 0; g < 6; ++g) {
        const float* Wp  = (g < 3) ? Wih : Whh;
        const float* src = Wp + (size_t)((g % 3) * 128 + w * 16 + l15) * 128 + q * 8;
        #pragma unroll
        for (int s = 0; s < 4; ++s) {
            f32x4 a = *(const f32x4*)(src + s * 32);
            f32x4 b = *(const f32x4*)(src + s * 32 + 4);
            wf[g][s] = pack8(a, b);
        }
    }

    // ---- per-lane biases for this lane's 4 h-cols ----
    const int h0 = w * 16 + q * 4;
    f32x4 br4  = *(const f32x4*)(bih + h0)       + *(const f32x4*)(bhh + h0);
    f32x4 bz4  = *(const f32x4*)(bih + 128 + h0) + *(const f32x4*)(bhh + 128 + h0);
    f32x4 bin4 = *(const f32x4*)(bih + 256 + h0);
    f32x4 bhn4 = *(const f32x4*)(bhh + 256 + h0);

    // ---- tile range ----
    const int t0 = blockIdx.x * tpb;
    const int t1 = (t0 + tpb < ntiles) ? (t0 + tpb) : ntiles;
    if (t0 >= t1) return;

    // ---- staging geometry: waves 0-3 stage x, 4-7 stage hid (2KB fp32 each) ----
    const int    sw   = w & 3;
    const float* gsrc = (w < 4) ? x : hid;
    const int    lreg = (w < 4) ? 0 : 4096;
    const int    r0    = sw * 4 + (lane >> 5);          // bf16 row for chunk 0
    const int    inrow = (lane & 31) * 8;               // byte within 256B row
    const int    dst0  = lreg + r0 * 256 + (inrow ^ ((r0 & 7) << 4));
    const int    dst1  = lreg + (r0 + 2) * 256 + (inrow ^ (((r0 + 2) & 7) << 4));

    // fragment read offsets (loop-invariant, swizzle matches write side)
    int xoff[4];
    #pragma unroll
    for (int s = 0; s < 4; ++s)
        xoff[s] = l15 * 256 + ((s * 64 + q * 16) ^ ((l15 & 7) << 4));

    const float* gp    = gsrc + (size_t)t0 * 2048 + sw * 512 + lane * 4;
    const float* hvp   = hid  + (size_t)(t0 * 16 + l15) * 128 + h0;
    float*       yp    = y    + (size_t)(t0 * 16 + l15) * 128 + h0;
    float*       houtp = hout + (size_t)t0 * 2048 + sw * 512 + lane * 4;

    // ---- prologue: load stage-set A (tile t0) ----
    f32x4 sa0 = *(const f32x4*)gp;
    f32x4 sa1 = *(const f32x4*)(gp + 256);
    f32x4 sb0, sb1;

    for (int t = t0; t < t1; t += 2) {
        const bool has1 = (t + 1 < t1);
        // prefetch tile t+1 into set B (a full tile of cover before use)
        if (has1) { gp += 2048; sb0 = *(const f32x4*)gp; sb1 = *(const f32x4*)(gp + 256); }
        // stage tile t (set A) -> buf0, bf16, swizzled
        *(short4v*)(lds[0] + dst0) = cvt4(sa0);
        *(short4v*)(lds[0] + dst1) = cvt4(sa1);
        __syncthreads();
        COMPUTE_TILE(lds[0], sa0, sa1);

        if (has1) {
            if (t + 2 < t1) { gp += 2048; sa0 = *(const f32x4*)gp; sa1 = *(const f32x4*)(gp + 256); }
            *(short4v*)(lds[1] + dst0) = cvt4(sb0);
            *(short4v*)(lds[1] + dst1) = cvt4(sb1);
            __syncthreads();
            COMPUTE_TILE(lds[1], sb0, sb1);
        } else {
            __syncthreads();   // odd tail: protect buf0 before next loop's write
        }
    }
}

extern "C" void kernel_launch(void* const* d_in, const int* in_sizes, int n_in,
                              void* d_out, int out_size, void* d_ws, size_t ws_size,
                              hipStream_t stream) {
    const float* x   = (const float*)d_in[0];
    const float* hid = (const float*)d_in[1];
    const float* Wih = (const float*)d_in[2];
    const float* Whh = (const float*)d_in[3];
    const float* bih = (const float*)d_in[4];
    const float* bhh = (const float*)d_in[5];

    const int M = in_sizes[0] / 128;               // T*B = 131072
    float* y    = (float*)d_out;
    float* hout = y + (size_t)M * 128;

    const int ntiles = M / 16;                     // 8192 row-tiles
    int grid = GRID;
    if (grid > ntiles) grid = ntiles;
    const int tpb = (ntiles + grid - 1) / grid;    // 8 tiles/block at M=131072

    gru_kernel<<<grid, 512, 0, stream>>>(x, hid, Wih, Whh, bih, bhh, y, hout, ntiles, tpb);
}